// Round 3
// baseline (145.253 us; speedup 1.0000x reference)
//
#include <hip/hip_runtime.h>

// Max-unpool (DePooling2D), B=8 H=56 W=56 C=256 stride=2 -> out (8,112,112,256) f32.
//
// Reference: scatter-add of net values to mask-encoded argmax positions.
// Windows are disjoint (stride == window) and every mask entry lies inside its
// own 2x2 window, so each output element has at most one contributor. Exact
// reformulation as a per-window EXPAND:
//   one thread owns one pooled cell's float4 (b,h,w,f..f+3); it reads
//   mask/net once and writes the 4 window positions (2x2), selecting
//   net where mask matches the TF argmax encoding ((y*oW+x)*C+f), else 0.
// -> mask/net fetched exactly once (no cache-dependent reuse), every output
//    byte written exactly once, all accesses 16B/lane coalesced.
// One wave (64 lanes x float4 = 256 ch = C) covers exactly one pooled cell,
// so each of the 4 window stores is a contiguous 1 KiB segment.
//
// P4 = 6272 * 256 exactly -> one-shot exact-cover launch, no loop, no tail.

namespace {
constexpr int B   = 8;
constexpr int H   = 56;
constexpr int Wd  = 56;
constexpr int C   = 256;          // power of two
constexpr int C4  = C / 4;        // 64 float4 per cell == one wave
constexpr int oW  = Wd * 2;
constexpr int oH  = H * 2;
constexpr int ROWSTRIDE = oW * C; // 28672 floats between output rows
constexpr int P4  = B * H * Wd * C4;   // 1,605,632 pooled float4 cells
constexpr int BLOCK = 256;
constexpr int GRID  = P4 / BLOCK;      // 6272, exact

typedef float f4 __attribute__((ext_vector_type(4)));
typedef int   i4 __attribute__((ext_vector_type(4)));

__device__ __forceinline__ f4 sel(const i4 m, const f4 v, int expected) {
  f4 r;
  r[0] = (m[0] == expected)     ? v[0] : 0.0f;
  r[1] = (m[1] == expected + 1) ? v[1] : 0.0f;
  r[2] = (m[2] == expected + 2) ? v[2] : 0.0f;
  r[3] = (m[3] == expected + 3) ? v[3] : 0.0f;
  return r;
}
}

__global__ __launch_bounds__(256) void unpool_expand(
    const float* __restrict__ net,
    const int*   __restrict__ mask,
    float*       __restrict__ out) {
  const int t = blockIdx.x * BLOCK + threadIdx.x;   // one pooled float4 cell

  const int f    = (t & (C4 - 1)) * 4;   // channel base
  const int cell = t >> 6;               // b*H*W + h*W + w
  const int w    = cell % Wd;            // const divisors -> magic multiply
  const int rest = cell / Wd;
  const int h    = rest % H;
  const int b    = rest / H;

  const int mi = t * 4;                  // pooled flat idx (same layout)
  const i4 m = *reinterpret_cast<const i4*>(mask + mi);   // 16B, read once
  const f4 v = *reinterpret_cast<const f4*>(net + mi);    // 16B, read once

  const int y0 = 2 * h, x0 = 2 * w;
  // TF argmax encoding (no batch term): ((y*oW)+x)*C + f
  const int e00 = (y0 * oW + x0) * C + f;
  const int e01 = e00 + C;
  const int e10 = e00 + ROWSTRIDE;
  const int e11 = e10 + C;

  // Output base for (b, y0, x0, f)
  const int o00 = ((b * oH + y0) * oW + x0) * C + f;
  f4* __restrict__ r0 = reinterpret_cast<f4*>(out + o00);
  f4* __restrict__ r1 = reinterpret_cast<f4*>(out + o00 + ROWSTRIDE);

  r0[0]  = sel(m, v, e00);   // (y0,   x0  )
  r0[C4] = sel(m, v, e01);   // (y0,   x0+1)  (+C floats = +C4 f4)
  r1[0]  = sel(m, v, e10);   // (y0+1, x0  )
  r1[C4] = sel(m, v, e11);   // (y0+1, x0+1)
}

extern "C" void kernel_launch(void* const* d_in, const int* in_sizes, int n_in,
                              void* d_out, int out_size, void* d_ws, size_t ws_size,
                              hipStream_t stream) {
  const float* net  = (const float*)d_in[0];
  const int*   mask = (const int*)d_in[1];
  // d_in[2] is the python scalar stride (=2), baked in.
  float* out = (float*)d_out;

  unpool_expand<<<GRID, BLOCK, 0, stream>>>(net, mask, out);
}